// Round 1
// baseline (293.221 us; speedup 1.0000x reference)
//
#include <hip/hip_runtime.h>

// AvgPool2d via fixed Toeplitz matmul, computed directly as a pooled sum.
//
// Structure exploited (see reference _build_toeplitz): the avg-pool "kernel"
// is ones(C,C,kh,kw)/(kh*kw), so
//   out[b, co, oy, ox] = 0.25 * sum_{ci,ky,kx} x[b, ci, 2*oy+ky, 2*ox+kx]
// and the value is IDENTICAL for all co. We compute the [B,Ho,Wo] pooled
// sums once and fan each value out to all C output channels.
// Traffic: 4 MB read + 1 MB write vs 260 MB for the literal GEMM.

#define B_  64
#define C_  16
#define H_  32
#define W_  32
#define HO_ 16
#define WO_ 16

__global__ __launch_bounds__(64)
void AvgPool2d_63539746177448_kernel(const float* __restrict__ x,
                                     float* __restrict__ out) {
    // grid.x = B_ * 4: blockIdx -> (b, quarter of oy rows)
    const int b  = blockIdx.x >> 2;
    const int q  = blockIdx.x & 3;
    const int t  = threadIdx.x;          // 64 threads: 4 oy rows x 16 ox
    const int oy = q * 4 + (t >> 4);
    const int ox = t & 15;

    const float* xb = x + b * (C_ * H_ * W_);
    const int base = (oy * 2) * W_ + (ox * 2);   // 8-byte aligned (ox*2 even)

    float s = 0.0f;
#pragma unroll
    for (int ci = 0; ci < C_; ++ci) {
        const float* p = xb + ci * (H_ * W_) + base;
        const float2 r0 = *reinterpret_cast<const float2*>(p);
        const float2 r1 = *reinterpret_cast<const float2*>(p + W_);
        s += (r0.x + r0.y) + (r1.x + r1.y);
    }
    s *= 0.25f;

    // out[b, co*Ho*Wo + oy*Wo + ox], same value for every co.
    float* ob = out + b * (C_ * HO_ * WO_) + oy * WO_ + ox;
#pragma unroll
    for (int co = 0; co < C_; ++co) {
        ob[co * (HO_ * WO_)] = s;
    }
}

extern "C" void kernel_launch(void* const* d_in, const int* in_sizes, int n_in,
                              void* d_out, int out_size, void* d_ws, size_t ws_size,
                              hipStream_t stream) {
    const float* enc_x = (const float*)d_in[0];   // [64, 16384] fp32
    // d_in[1] (toeplitz, [4096,16384]) is structurally fixed -- not read.
    float* out = (float*)d_out;                   // [64, 4096] fp32

    AvgPool2d_63539746177448_kernel<<<B_ * 4, 64, 0, stream>>>(enc_x, out);
}